// Round 4
// baseline (1477.028 us; speedup 1.0000x reference)
//
#include <hip/hip_runtime.h>
#include <hip/hip_bf16.h>
#include <stdint.h>

// Problem constants
#define BATCH   8192
#define IN_DIM  1024
#define N_HID   2048
#define OUT_DIM 256
#define SRC_DIM 3072

// Tiling
#define C     32                   // source columns per chunk
#define RB    32                   // rows per row-block (= rows per wave)
#define BT    128                  // batch elements per block (2 per lane)
#define S1_CH (IN_DIM / C)         // 32
#define S1_RB (N_HID / RB)         // 64
#define S2_CH (SRC_DIM / C)        // 96
#define S2_RB (OUT_DIM / RB)       // 8
#define NSEG1 (S1_RB * S1_CH)      // 2048
#define NSEG2 (S2_RB * S2_CH)      // 768
#define MAXW  8                    // max 4-slot record planes per row
#define SEG_U32 (MAXW * RB)        // 256 u32 per segment (1 KB)
#define ZSLOT 128                  // A-tile zero page slot (pad byte 0x80)

// ---------------------------------------------------------------------------
// k_prep: one wave per (row-block, chunk) segment. Lane r (<32) scans its
// row's 32 codes and scatters slot bytes (t*32+c) into plane-major records:
// rec[p][r] u32 = 4 slot bytes. Pad bytes from 0x80 memset. hdr = ceil(max/4).
// ---------------------------------------------------------------------------
__global__ void k_prep(const int* __restrict__ mat,
                       uint32_t* __restrict__ seg1, uint32_t* __restrict__ seg2,
                       uint32_t* __restrict__ hdr1, uint32_t* __restrict__ hdr2) {
    int wid  = (blockIdx.x * blockDim.x + threadIdx.x) >> 6;
    int lane = threadIdx.x & 63;
    if (wid >= NSEG1 + NSEG2) return;

    int row0, col0;
    uint32_t *seg, *hdr;
    if (wid < NSEG1) {
        int rb = wid / S1_CH, ch = wid % S1_CH;
        row0 = rb * RB;          col0 = ch * C;
        seg = seg1 + (size_t)wid * SEG_U32;  hdr = hdr1 + wid;
    } else {
        int s  = wid - NSEG1;
        int rb = s / S2_CH, ch = s % S2_CH;
        row0 = N_HID + rb * RB;  col0 = ch * C;
        seg = seg2 + (size_t)s * SEG_U32;    hdr = hdr2 + s;
    }

    int n = 0;
    if (lane < RB) {
        const int* mrow = mat + (size_t)(row0 + lane) * SRC_DIM + col0;
        uint8_t* sb = (uint8_t*)seg;
        for (int c = 0; c < C; c++) {
            int code = mrow[c];
            if (code != 0) {
                sb[(size_t)(n >> 2) * (RB * 4) + lane * 4 + (n & 3)] =
                    (uint8_t)((code - 1) * C + c);
                n++;
            }
        }
    }
    int m = n;
    #pragma unroll
    for (int d = 1; d < 64; d <<= 1) m = max(m, __shfl_xor(m, d));
    if (lane == 0) *hdr = (uint32_t)((m + 3) >> 2);
}

// pack two floats as bf16 pair: low16 = a (batch b), high16 = b (batch b+64)
__device__ __forceinline__ uint32_t pack2(float a, float b) {
    __hip_bfloat162 h = __float22bfloat162_rn(make_float2(a, b));
    union { __hip_bfloat162 h2; uint32_t u; } u;
    u.h2 = h;
    return u.u;
}

// A-tile: As[slot*64 + lane] u32 = bf16 pair; slot = t*32+c; slot 128 = zeros.
__device__ __forceinline__ void write_acts2(uint32_t* As, int c, int lane,
                                            float va, float vb) {
    As[(0 * C + c) * 64 + lane] = pack2(va, vb);
    As[(1 * C + c) * 64 + lane] = pack2(fmaxf(va, 0.0f), fmaxf(vb, 0.0f));
    float ta = 1.0f - 2.0f / (__expf(2.0f * va) + 1.0f);
    float tb = 1.0f - 2.0f / (__expf(2.0f * vb) + 1.0f);
    As[(2 * C + c) * 64 + lane] = pack2(ta, tb);
    float sa = 1.0f / (1.0f + __expf(-va));
    float sb = 1.0f / (1.0f + __expf(-vb));
    As[(3 * C + c) * 64 + lane] = pack2(sa, sb);
}

#define ACC_ROW_BODY(G)                                                        \
    {                                                                          \
        uint32_t q0 = As[((G) & 255u) * 64 + lane];                            \
        uint32_t q1 = As[(((G) >> 8) & 255u) * 64 + lane];                     \
        uint32_t q2 = As[(((G) >> 16) & 255u) * 64 + lane];                    \
        uint32_t q3 = As[((G) >> 24) * 64 + lane];                             \
        xa += __uint_as_float(q0 << 16); xb += __uint_as_float(q0 & 0xFFFF0000u); \
        xa += __uint_as_float(q1 << 16); xb += __uint_as_float(q1 & 0xFFFF0000u); \
        xa += __uint_as_float(q2 << 16); xb += __uint_as_float(q2 & 0xFFFF0000u); \
        xa += __uint_as_float(q3 << 16); xb += __uint_as_float(q3 & 0xFFFF0000u); \
    }

#define EDGE_PLANES(SEGBASE, WVAL)                                             \
    {                                                                          \
        const uint32_t* rec_ = (SEGBASE);                                      \
        _Pragma("unroll")                                                      \
        for (int r = 0; r < RB; r++) {                                         \
            uint32_t g = rec_[r];                                              \
            float xa = accA[r], xb = accB[r];                                  \
            ACC_ROW_BODY(g)                                                    \
            accA[r] = xa; accB[r] = xb;                                        \
        }                                                                      \
        for (uint32_t p = 1; p < (WVAL); p++) {                                \
            const uint32_t* rp_ = rec_ + p * RB;                               \
            _Pragma("unroll")                                                  \
            for (int r = 0; r < RB; r++) {                                     \
                uint32_t g = rp_[r];                                           \
                if (g != 0x80808080u) {                                        \
                    float xa = accA[r], xb = accB[r];                          \
                    ACC_ROW_BODY(g)                                            \
                    accA[r] = xa; accB[r] = xb;                                \
                }                                                              \
            }                                                                  \
        }                                                                      \
    }

// ---------------------------------------------------------------------------
// Stage 1: block = 512 thr = 8 waves x 32 rows; lane pair = batch (b, b+64).
// Grid (64 batch tiles of 128, 8 row splits). hidden stored [row][batch].
// ---------------------------------------------------------------------------
__global__ __launch_bounds__(512, 4) void k_hid(const float* __restrict__ x,
                                                const float* __restrict__ wp,
                                                const uint32_t* __restrict__ seg1,
                                                const uint32_t* __restrict__ hdr1,
                                                __hip_bfloat16* __restrict__ hidden_t) {
    __shared__ uint32_t As[(4 * C + 1) * 64];   // 33 KB (bf16 pairs + zero page)
    __shared__ float xs[BT][C + 1];             // 16.9 KB

    const float w  = wp[0];
    const int tile = blockIdx.x;                // 0..63
    const int lane = threadIdx.x & 63;
    const int wv   = __builtin_amdgcn_readfirstlane(threadIdx.x >> 6);
    const int rb   = blockIdx.y * 8 + wv;       // 0..63

    if (threadIdx.x < 64) As[ZSLOT * 64 + threadIdx.x] = 0u;

    float accA[RB], accB[RB];
    #pragma unroll
    for (int r = 0; r < RB; r++) { accA[r] = 0.0f; accB[r] = 0.0f; }

    #pragma unroll 1
    for (int ch = 0; ch < S1_CH; ch++) {
        __syncthreads();
        // stage x tile: 128 b x 32 c fp32, float4 loads (2 quads / thread)
        #pragma unroll
        for (int k = 0; k < 2; k++) {
            int qq = threadIdx.x + k * 512;
            int b  = qq >> 3;
            int c4 = (qq & 7) * 4;
            float4 v = *(const float4*)&x[(size_t)(tile * BT + b) * IN_DIM + ch * C + c4];
            xs[b][c4 + 0] = v.x; xs[b][c4 + 1] = v.y;
            xs[b][c4 + 2] = v.z; xs[b][c4 + 3] = v.w;
        }
        __syncthreads();
        #pragma unroll
        for (int j = 0; j < 4; j++) {
            int c = wv * 4 + j;
            write_acts2(As, c, lane, w * xs[lane][c], w * xs[lane + 64][c]);
        }
        __syncthreads();
        int sidx = rb * S1_CH + ch;
        uint32_t W = hdr1[sidx];
        EDGE_PLANES(seg1 + (size_t)sidx * SEG_U32, W)
    }

    const int b0 = tile * BT + lane;
    const int row0 = rb * RB;
    #pragma unroll
    for (int r = 0; r < RB; r++) {
        hidden_t[(size_t)(row0 + r) * BATCH + b0]      = __float2bfloat16(accA[r]);
        hidden_t[(size_t)(row0 + r) * BATCH + b0 + 64] = __float2bfloat16(accB[r]);
    }
}

// ---------------------------------------------------------------------------
// Stage 2: block = 512 thr = 8 waves x 32 rows = all 256 out rows.
// Grid (64 tiles, 4 chunk groups of 24). Coalesced fp32 partials [cg][r][b].
// ---------------------------------------------------------------------------
__global__ __launch_bounds__(512, 4) void k_out(const float* __restrict__ x,
                                                const __hip_bfloat16* __restrict__ hidden_t,
                                                const float* __restrict__ wp,
                                                const uint32_t* __restrict__ seg2,
                                                const uint32_t* __restrict__ hdr2,
                                                float* __restrict__ partials) {
    __shared__ uint32_t As[(4 * C + 1) * 64];
    __shared__ float xs[BT][C + 1];

    const float w  = wp[0];
    const int tile = blockIdx.x;                // 0..63
    const int cg   = blockIdx.y;                // 0..3
    const int lane = threadIdx.x & 63;
    const int wv   = __builtin_amdgcn_readfirstlane(threadIdx.x >> 6);

    if (threadIdx.x < 64) As[ZSLOT * 64 + threadIdx.x] = 0u;

    float accA[RB], accB[RB];
    #pragma unroll
    for (int r = 0; r < RB; r++) { accA[r] = 0.0f; accB[r] = 0.0f; }

    #pragma unroll 1
    for (int cj = 0; cj < 24; cj++) {
        int ch   = cg * 24 + cj;
        int col0 = ch * C;
        __syncthreads();
        if (col0 < IN_DIM) {                    // x region: float4, coalesced
            #pragma unroll
            for (int k = 0; k < 2; k++) {
                int qq = threadIdx.x + k * 512;
                int b  = qq >> 3;
                int c4 = (qq & 7) * 4;
                float4 v = *(const float4*)&x[(size_t)(tile * BT + b) * IN_DIM + col0 + c4];
                xs[b][c4 + 0] = v.x; xs[b][c4 + 1] = v.y;
                xs[b][c4 + 2] = v.z; xs[b][c4 + 3] = v.w;
            }
        } else {                                // hidden_t: coalesced along b
            int b  = threadIdx.x & 127;
            int c0 = threadIdx.x >> 7;          // 0..3
            #pragma unroll
            for (int k = 0; k < 8; k++) {
                int c = c0 + 4 * k;
                xs[b][c] = __bfloat162float(
                    hidden_t[(size_t)(col0 - IN_DIM + c) * BATCH + tile * BT + b]);
            }
        }
        __syncthreads();
        #pragma unroll
        for (int j = 0; j < 4; j++) {
            int c = wv * 4 + j;
            write_acts2(As, c, lane, w * xs[lane][c], w * xs[lane + 64][c]);
        }
        __syncthreads();
        int sidx = wv * S2_CH + ch;
        uint32_t W = hdr2[sidx];
        EDGE_PLANES(seg2 + (size_t)sidx * SEG_U32, W)
    }

    const int b0 = tile * BT + lane;
    #pragma unroll
    for (int r = 0; r < RB; r++) {
        size_t base = ((size_t)cg * OUT_DIM + wv * RB + r) * BATCH;
        partials[base + b0]      = accA[r];
        partials[base + b0 + 64] = accB[r];
    }
}

// ---------------------------------------------------------------------------
// k_sum: reduce 4 partial planes + transpose [r][b] -> out[b][r] (float4).
// ---------------------------------------------------------------------------
__global__ __launch_bounds__(256) void k_sum(const float* __restrict__ partials,
                                             float* __restrict__ out) {
    __shared__ float t[16][65];
    const int b0 = blockIdx.x * 64, r0 = blockIdx.y * 16;
    const int lane = threadIdx.x & 63;
    const int g4   = threadIdx.x >> 6;

    #pragma unroll
    for (int k = 0; k < 4; k++) {
        int rr = g4 * 4 + k;
        float s = 0.0f;
        #pragma unroll
        for (int cg = 0; cg < 4; cg++)
            s += partials[((size_t)cg * OUT_DIM + r0 + rr) * BATCH + b0 + lane];
        t[rr][lane] = s;
    }
    __syncthreads();
    int bb = threadIdx.x >> 2, rq = threadIdx.x & 3;
    float4 v;
    v.x = t[rq * 4 + 0][bb];
    v.y = t[rq * 4 + 1][bb];
    v.z = t[rq * 4 + 2][bb];
    v.w = t[rq * 4 + 3][bb];
    *(float4*)&out[(size_t)(b0 + bb) * OUT_DIM + r0 + rq * 4] = v;
}

// ---------------------------------------------------------------------------
extern "C" void kernel_launch(void* const* d_in, const int* in_sizes, int n_in,
                              void* d_out, int out_size, void* d_ws, size_t ws_size,
                              hipStream_t stream) {
    const float* x   = (const float*)d_in[0];
    const float* w   = (const float*)d_in[1];
    const int*   mat = (const int*)d_in[2];
    float* out = (float*)d_out;

    uint8_t* ws = (uint8_t*)d_ws;
    size_t off = 0;
    __hip_bfloat16* hidden_t = (__hip_bfloat16*)(ws + off); off += (size_t)BATCH * N_HID * 2;  // 33.55 MB
    uint32_t* seg1 = (uint32_t*)(ws + off); off += (size_t)NSEG1 * SEG_U32 * 4;                //  2.10 MB
    uint32_t* seg2 = (uint32_t*)(ws + off); off += (size_t)NSEG2 * SEG_U32 * 4;                //  0.79 MB
    uint32_t* hdr1 = (uint32_t*)(ws + off); off += (size_t)NSEG1 * 4;
    uint32_t* hdr2 = (uint32_t*)(ws + off); off += (size_t)NSEG2 * 4;
    float* partials = (float*)(ws + off);   off += (size_t)4 * OUT_DIM * BATCH * 4;            // 33.55 MB
    (void)ws_size; (void)in_sizes; (void)n_in; (void)out_size;

    hipMemsetAsync(seg1, 0x80, (size_t)(NSEG1 + NSEG2) * SEG_U32 * 4, stream);

    {
        int nseg = NSEG1 + NSEG2;
        k_prep<<<(nseg + 3) / 4, 256, 0, stream>>>(mat, seg1, seg2, hdr1, hdr2);
    }
    {
        dim3 g(BATCH / BT, 8);                 // 64 x 8 = 512 blocks
        k_hid<<<g, 512, 0, stream>>>(x, w, seg1, hdr1, hidden_t);
    }
    {
        dim3 g(BATCH / BT, 4);                 // 64 x 4 = 256 blocks
        k_out<<<g, 512, 0, stream>>>(x, hidden_t, w, seg2, hdr2, partials);
    }
    {
        dim3 g(BATCH / 64, OUT_DIM / 16);      // 2048 blocks
        k_sum<<<g, 256, 0, stream>>>(partials, out);
    }
}

// Round 5
// 616.354 us; speedup vs baseline: 2.3964x; 2.3964x over previous
//
#include <hip/hip_runtime.h>
#include <hip/hip_bf16.h>
#include <stdint.h>

// Problem constants
#define BATCH   8192
#define IN_DIM  1024
#define N_HID   2048
#define OUT_DIM 256
#define SRC_DIM 3072

// Tiling
#define C     32                   // source columns per chunk
#define RB    32                   // rows per row-block (= rows per wave)
#define BT    128                  // batch elements per block (2 per lane)
#define S1_CH (IN_DIM / C)         // 32
#define S1_RB (N_HID / RB)         // 64
#define S2_CH (SRC_DIM / C)        // 96
#define S2_RB (OUT_DIM / RB)       // 8
#define NSEG1 (S1_RB * S1_CH)      // 2048
#define NSEG2 (S2_RB * S2_CH)      // 768
#define MAXW  8                    // max 4-slot record planes per row
#define SEG_U32 (MAXW * RB)        // 256 u32 per segment (1 KB)
#define ZSLOT 128                  // A-tile zero page slot (pad byte 0x80)

// NOTE (measured R1/R4): with 512-thread blocks this compiler treats the 2nd
// __launch_bounds__ arg such that 4 -> 64-VGPR cap (spills acc arrays!).
// Use 2 -> 128-VGPR cap; accA+accB (~100 VGPR) fit, residency 2 blocks/CU.

// ---------------------------------------------------------------------------
// k_prep: one wave per (row-block, chunk) segment. Lane r (<32) scans its
// row's 32 codes and scatters slot bytes (t*32+c) into plane-major records:
// rec[p][r] u32 = 4 slot bytes. Pad bytes from 0x80 memset. hdr = ceil(max/4).
// ---------------------------------------------------------------------------
__global__ void k_prep(const int* __restrict__ mat,
                       uint32_t* __restrict__ seg1, uint32_t* __restrict__ seg2,
                       uint32_t* __restrict__ hdr1, uint32_t* __restrict__ hdr2) {
    int wid  = (blockIdx.x * blockDim.x + threadIdx.x) >> 6;
    int lane = threadIdx.x & 63;
    if (wid >= NSEG1 + NSEG2) return;

    int row0, col0;
    uint32_t *seg, *hdr;
    if (wid < NSEG1) {
        int rb = wid / S1_CH, ch = wid % S1_CH;
        row0 = rb * RB;          col0 = ch * C;
        seg = seg1 + (size_t)wid * SEG_U32;  hdr = hdr1 + wid;
    } else {
        int s  = wid - NSEG1;
        int rb = s / S2_CH, ch = s % S2_CH;
        row0 = N_HID + rb * RB;  col0 = ch * C;
        seg = seg2 + (size_t)s * SEG_U32;    hdr = hdr2 + s;
    }

    int n = 0;
    if (lane < RB) {
        const int* mrow = mat + (size_t)(row0 + lane) * SRC_DIM + col0;
        uint8_t* sb = (uint8_t*)seg;
        for (int c = 0; c < C; c++) {
            int code = mrow[c];
            if (code != 0) {
                sb[(size_t)(n >> 2) * (RB * 4) + lane * 4 + (n & 3)] =
                    (uint8_t)((code - 1) * C + c);
                n++;
            }
        }
    }
    int m = n;
    #pragma unroll
    for (int d = 1; d < 64; d <<= 1) m = max(m, __shfl_xor(m, d));
    if (lane == 0) *hdr = (uint32_t)((m + 3) >> 2);
}

// pack two floats as bf16 pair: low16 = a (batch b), high16 = b (batch b+64)
__device__ __forceinline__ uint32_t pack2(float a, float b) {
    __hip_bfloat162 h = __float22bfloat162_rn(make_float2(a, b));
    union { __hip_bfloat162 h2; uint32_t u; } u;
    u.h2 = h;
    return u.u;
}

// A-tile: As[slot*64 + lane] u32 = bf16 pair; slot = t*32+c; slot 128 = zeros.
__device__ __forceinline__ void write_acts2(uint32_t* As, int c, int lane,
                                            float va, float vb) {
    As[(0 * C + c) * 64 + lane] = pack2(va, vb);
    As[(1 * C + c) * 64 + lane] = pack2(fmaxf(va, 0.0f), fmaxf(vb, 0.0f));
    float ta = 1.0f - 2.0f / (__expf(2.0f * va) + 1.0f);
    float tb = 1.0f - 2.0f / (__expf(2.0f * vb) + 1.0f);
    As[(2 * C + c) * 64 + lane] = pack2(ta, tb);
    float sa = 1.0f / (1.0f + __expf(-va));
    float sb = 1.0f / (1.0f + __expf(-vb));
    As[(3 * C + c) * 64 + lane] = pack2(sa, sb);
}

#define ACC_ROW_BODY(G)                                                        \
    {                                                                          \
        uint32_t q0 = As[((G) & 255u) * 64 + lane];                            \
        uint32_t q1 = As[(((G) >> 8) & 255u) * 64 + lane];                     \
        uint32_t q2 = As[(((G) >> 16) & 255u) * 64 + lane];                    \
        uint32_t q3 = As[((G) >> 24) * 64 + lane];                             \
        xa += __uint_as_float(q0 << 16); xb += __uint_as_float(q0 & 0xFFFF0000u); \
        xa += __uint_as_float(q1 << 16); xb += __uint_as_float(q1 & 0xFFFF0000u); \
        xa += __uint_as_float(q2 << 16); xb += __uint_as_float(q2 & 0xFFFF0000u); \
        xa += __uint_as_float(q3 << 16); xb += __uint_as_float(q3 & 0xFFFF0000u); \
    }

#define EDGE_PLANES(SEGBASE, WVAL)                                             \
    {                                                                          \
        const uint32_t* rec_ = (SEGBASE);                                      \
        _Pragma("unroll")                                                      \
        for (int r = 0; r < RB; r++) {                                         \
            uint32_t g = rec_[r];                                              \
            float xa = accA[r], xb = accB[r];                                  \
            ACC_ROW_BODY(g)                                                    \
            accA[r] = xa; accB[r] = xb;                                        \
        }                                                                      \
        for (uint32_t p = 1; p < (WVAL); p++) {                                \
            const uint32_t* rp_ = rec_ + p * RB;                               \
            _Pragma("unroll")                                                  \
            for (int r = 0; r < RB; r++) {                                     \
                uint32_t g = rp_[r];                                           \
                if (g != 0x80808080u) {                                        \
                    float xa = accA[r], xb = accB[r];                          \
                    ACC_ROW_BODY(g)                                            \
                    accA[r] = xa; accB[r] = xb;                                \
                }                                                              \
            }                                                                  \
        }                                                                      \
    }

// ---------------------------------------------------------------------------
// Stage 1: block = 512 thr = 8 waves x 32 rows; lane pair = batch (b, b+64).
// Grid (64 batch tiles of 128, 8 row splits). hidden stored [row][batch].
// ---------------------------------------------------------------------------
__global__ __launch_bounds__(512, 2) void k_hid(const float* __restrict__ x,
                                                const float* __restrict__ wp,
                                                const uint32_t* __restrict__ seg1,
                                                const uint32_t* __restrict__ hdr1,
                                                __hip_bfloat16* __restrict__ hidden_t) {
    __shared__ uint32_t As[(4 * C + 1) * 64];   // 33 KB (bf16 pairs + zero page)
    __shared__ float xs[BT][C + 1];             // 16.9 KB

    const float w  = wp[0];
    const int tile = blockIdx.x;                // 0..63
    const int lane = threadIdx.x & 63;
    const int wv   = __builtin_amdgcn_readfirstlane(threadIdx.x >> 6);
    const int rb   = blockIdx.y * 8 + wv;       // 0..63

    if (threadIdx.x < 64) As[ZSLOT * 64 + threadIdx.x] = 0u;

    float accA[RB], accB[RB];
    #pragma unroll
    for (int r = 0; r < RB; r++) { accA[r] = 0.0f; accB[r] = 0.0f; }

    #pragma unroll 1
    for (int ch = 0; ch < S1_CH; ch++) {
        __syncthreads();
        // stage x tile: 128 b x 32 c fp32, float4 loads (2 quads / thread)
        #pragma unroll
        for (int k = 0; k < 2; k++) {
            int qq = threadIdx.x + k * 512;
            int b  = qq >> 3;
            int c4 = (qq & 7) * 4;
            float4 v = *(const float4*)&x[(size_t)(tile * BT + b) * IN_DIM + ch * C + c4];
            xs[b][c4 + 0] = v.x; xs[b][c4 + 1] = v.y;
            xs[b][c4 + 2] = v.z; xs[b][c4 + 3] = v.w;
        }
        __syncthreads();
        #pragma unroll
        for (int j = 0; j < 4; j++) {
            int c = wv * 4 + j;
            write_acts2(As, c, lane, w * xs[lane][c], w * xs[lane + 64][c]);
        }
        __syncthreads();
        int sidx = rb * S1_CH + ch;
        uint32_t W = hdr1[sidx];
        EDGE_PLANES(seg1 + (size_t)sidx * SEG_U32, W)
    }

    const int b0 = tile * BT + lane;
    const int row0 = rb * RB;
    #pragma unroll
    for (int r = 0; r < RB; r++) {
        hidden_t[(size_t)(row0 + r) * BATCH + b0]      = __float2bfloat16(accA[r]);
        hidden_t[(size_t)(row0 + r) * BATCH + b0 + 64] = __float2bfloat16(accB[r]);
    }
}

// ---------------------------------------------------------------------------
// Stage 2: block = 512 thr = 8 waves x 32 rows = all 256 out rows.
// Grid (64 tiles, 4 chunk groups of 24). Coalesced fp32 partials [cg][r][b].
// ---------------------------------------------------------------------------
__global__ __launch_bounds__(512, 2) void k_out(const float* __restrict__ x,
                                                const __hip_bfloat16* __restrict__ hidden_t,
                                                const float* __restrict__ wp,
                                                const uint32_t* __restrict__ seg2,
                                                const uint32_t* __restrict__ hdr2,
                                                float* __restrict__ partials) {
    __shared__ uint32_t As[(4 * C + 1) * 64];
    __shared__ float xs[BT][C + 1];

    const float w  = wp[0];
    const int tile = blockIdx.x;                // 0..63
    const int cg   = blockIdx.y;                // 0..3
    const int lane = threadIdx.x & 63;
    const int wv   = __builtin_amdgcn_readfirstlane(threadIdx.x >> 6);

    if (threadIdx.x < 64) As[ZSLOT * 64 + threadIdx.x] = 0u;

    float accA[RB], accB[RB];
    #pragma unroll
    for (int r = 0; r < RB; r++) { accA[r] = 0.0f; accB[r] = 0.0f; }

    #pragma unroll 1
    for (int cj = 0; cj < 24; cj++) {
        int ch   = cg * 24 + cj;
        int col0 = ch * C;
        __syncthreads();
        if (col0 < IN_DIM) {                    // x region: float4, coalesced
            #pragma unroll
            for (int k = 0; k < 2; k++) {
                int qq = threadIdx.x + k * 512;
                int b  = qq >> 3;
                int c4 = (qq & 7) * 4;
                float4 v = *(const float4*)&x[(size_t)(tile * BT + b) * IN_DIM + col0 + c4];
                xs[b][c4 + 0] = v.x; xs[b][c4 + 1] = v.y;
                xs[b][c4 + 2] = v.z; xs[b][c4 + 3] = v.w;
            }
        } else {                                // hidden_t: coalesced along b
            int b  = threadIdx.x & 127;
            int c0 = threadIdx.x >> 7;          // 0..3
            #pragma unroll
            for (int k = 0; k < 8; k++) {
                int c = c0 + 4 * k;
                xs[b][c] = __bfloat162float(
                    hidden_t[(size_t)(col0 - IN_DIM + c) * BATCH + tile * BT + b]);
            }
        }
        __syncthreads();
        #pragma unroll
        for (int j = 0; j < 4; j++) {
            int c = wv * 4 + j;
            write_acts2(As, c, lane, w * xs[lane][c], w * xs[lane + 64][c]);
        }
        __syncthreads();
        int sidx = wv * S2_CH + ch;
        uint32_t W = hdr2[sidx];
        EDGE_PLANES(seg2 + (size_t)sidx * SEG_U32, W)
    }

    const int b0 = tile * BT + lane;
    #pragma unroll
    for (int r = 0; r < RB; r++) {
        size_t base = ((size_t)cg * OUT_DIM + wv * RB + r) * BATCH;
        partials[base + b0]      = accA[r];
        partials[base + b0 + 64] = accB[r];
    }
}

// ---------------------------------------------------------------------------
// k_sum: reduce 4 partial planes + transpose [r][b] -> out[b][r] (float4).
// ---------------------------------------------------------------------------
__global__ __launch_bounds__(256) void k_sum(const float* __restrict__ partials,
                                             float* __restrict__ out) {
    __shared__ float t[16][65];
    const int b0 = blockIdx.x * 64, r0 = blockIdx.y * 16;
    const int lane = threadIdx.x & 63;
    const int g4   = threadIdx.x >> 6;

    #pragma unroll
    for (int k = 0; k < 4; k++) {
        int rr = g4 * 4 + k;
        float s = 0.0f;
        #pragma unroll
        for (int cg = 0; cg < 4; cg++)
            s += partials[((size_t)cg * OUT_DIM + r0 + rr) * BATCH + b0 + lane];
        t[rr][lane] = s;
    }
    __syncthreads();
    int bb = threadIdx.x >> 2, rq = threadIdx.x & 3;
    float4 v;
    v.x = t[rq * 4 + 0][bb];
    v.y = t[rq * 4 + 1][bb];
    v.z = t[rq * 4 + 2][bb];
    v.w = t[rq * 4 + 3][bb];
    *(float4*)&out[(size_t)(b0 + bb) * OUT_DIM + r0 + rq * 4] = v;
}

// ---------------------------------------------------------------------------
extern "C" void kernel_launch(void* const* d_in, const int* in_sizes, int n_in,
                              void* d_out, int out_size, void* d_ws, size_t ws_size,
                              hipStream_t stream) {
    const float* x   = (const float*)d_in[0];
    const float* w   = (const float*)d_in[1];
    const int*   mat = (const int*)d_in[2];
    float* out = (float*)d_out;

    uint8_t* ws = (uint8_t*)d_ws;
    size_t off = 0;
    __hip_bfloat16* hidden_t = (__hip_bfloat16*)(ws + off); off += (size_t)BATCH * N_HID * 2;  // 33.55 MB
    uint32_t* seg1 = (uint32_t*)(ws + off); off += (size_t)NSEG1 * SEG_U32 * 4;                //  2.10 MB
    uint32_t* seg2 = (uint32_t*)(ws + off); off += (size_t)NSEG2 * SEG_U32 * 4;                //  0.79 MB
    uint32_t* hdr1 = (uint32_t*)(ws + off); off += (size_t)NSEG1 * 4;
    uint32_t* hdr2 = (uint32_t*)(ws + off); off += (size_t)NSEG2 * 4;
    float* partials = (float*)(ws + off);   off += (size_t)4 * OUT_DIM * BATCH * 4;            // 33.55 MB
    (void)ws_size; (void)in_sizes; (void)n_in; (void)out_size;

    hipMemsetAsync(seg1, 0x80, (size_t)(NSEG1 + NSEG2) * SEG_U32 * 4, stream);

    {
        int nseg = NSEG1 + NSEG2;
        k_prep<<<(nseg + 3) / 4, 256, 0, stream>>>(mat, seg1, seg2, hdr1, hdr2);
    }
    {
        dim3 g(BATCH / BT, 8);                 // 64 x 8 = 512 blocks
        k_hid<<<g, 512, 0, stream>>>(x, w, seg1, hdr1, hidden_t);
    }
    {
        dim3 g(BATCH / BT, 4);                 // 64 x 4 = 256 blocks
        k_out<<<g, 512, 0, stream>>>(x, hidden_t, w, seg2, hdr2, partials);
    }
    {
        dim3 g(BATCH / 64, OUT_DIM / 16);      // 2048 blocks
        k_sum<<<g, 256, 0, stream>>>(partials, out);
    }
}